// Round 11
// baseline (2328.530 us; speedup 1.0000x reference)
//
#include <hip/hip_runtime.h>
#include <hip/hip_bf16.h>

// MoE top-4 of 16 experts, T=8192 tokens, HID=1024, FFN=4096.
// R7: XOR-swizzled LDS (conflicts 1.03e8 -> 0, verified).
// R9: 2-phase double-buffered K-loop (+3%; barrier drain is structural).
// R10: non-GEMM overhaul — fat grid-stride wcvt, cvt_x fused into gating,
//      k_scan folded into k_scatter. GEMMs untouched (control).
// ws layout (peak ~400.5 MiB):
//   SLOT_A bf16 [E][N][K]   134217728 B  (W1T for ffn1, then W2T for ffn2)
//   XB  bf16 [T][HID]        16777216 B
//   HDN bf16 [4T][FFN]      268435456 B
//   LTOK/LW/TKE/TKW         4*131072  B
//   CTRL ints (counts/offsets/cursors)  256 B

#define HID 1024
#define FFN 4096
#define NE 16
#define TOPK 4
#define NTOK 8192
#define NPAIR (NTOK*TOPK)

typedef __attribute__((ext_vector_type(4))) float f32x4;
typedef __attribute__((ext_vector_type(8))) short bf16x8;
typedef unsigned short u16;
typedef unsigned int u32;

__device__ __forceinline__ u16 f2bf(float f){
  u32 u = __float_as_uint(f);
  u32 r = (u + 0x7fffu + ((u >> 16) & 1u)) >> 16;   // RNE
  return (u16)r;
}

__device__ __forceinline__ void gload_lds16(const void* g, void* l){
  __builtin_amdgcn_global_load_lds((const __attribute__((address_space(1))) void*)g,
                                   (__attribute__((address_space(3))) void*)l, 16, 0, 0);
}

// ---------------- gating (+ fused x->bf16 convert): one wave per token ----------------
__global__ __launch_bounds__(256) void k_gating(const float* __restrict__ x,
    const float* __restrict__ Wg, const float* __restrict__ bg,
    int* __restrict__ counts, int* __restrict__ tke, float* __restrict__ tkw,
    u16* __restrict__ xb){
  int t    = (blockIdx.x << 2) + (threadIdx.x >> 6);
  int lane = threadIdx.x & 63;
  const float* xr = x + (size_t)t*HID + lane*16;
  const float4* p = (const float4*)xr;
  float4 va = p[0], vb = p[1], vc = p[2], vd = p[3];
  float xv[16] = {va.x,va.y,va.z,va.w, vb.x,vb.y,vb.z,vb.w,
                  vc.x,vc.y,vc.z,vc.w, vd.x,vd.y,vd.z,vd.w};
  float acc[NE];
  #pragma unroll
  for (int e=0;e<NE;e++) acc[e] = 0.f;
  #pragma unroll
  for (int j=0;j<16;j++){
    const float* wr = Wg + (size_t)(lane*16 + j)*NE;
    #pragma unroll
    for (int e=0;e<NE;e++) acc[e] += xv[j] * wr[e];
  }
  // fused bf16 convert of x (all lanes)
  uint4 o0, o1;
  o0.x = (u32)f2bf(xv[0])  | ((u32)f2bf(xv[1])  << 16);
  o0.y = (u32)f2bf(xv[2])  | ((u32)f2bf(xv[3])  << 16);
  o0.z = (u32)f2bf(xv[4])  | ((u32)f2bf(xv[5])  << 16);
  o0.w = (u32)f2bf(xv[6])  | ((u32)f2bf(xv[7])  << 16);
  o1.x = (u32)f2bf(xv[8])  | ((u32)f2bf(xv[9])  << 16);
  o1.y = (u32)f2bf(xv[10]) | ((u32)f2bf(xv[11]) << 16);
  o1.z = (u32)f2bf(xv[12]) | ((u32)f2bf(xv[13]) << 16);
  o1.w = (u32)f2bf(xv[14]) | ((u32)f2bf(xv[15]) << 16);
  u16* xbr = xb + (size_t)t*HID + lane*16;
  *(uint4*)xbr       = o0;
  *(uint4*)(xbr + 8) = o1;

  #pragma unroll
  for (int off=32; off; off>>=1){
    #pragma unroll
    for (int e=0;e<NE;e++) acc[e] += __shfl_xor(acc[e], off);
  }
  if (lane == 0){
    #pragma unroll
    for (int e=0;e<NE;e++) acc[e] += bg[e];
    int te[TOPK]; float tv[TOPK];
    #pragma unroll
    for (int k=0;k<TOPK;k++){
      int bi = 0; float bv = -1e30f;
      #pragma unroll
      for (int e=0;e<NE;e++) if (acc[e] > bv){ bv = acc[e]; bi = e; }
      te[k] = bi; tv[k] = bv; acc[bi] = -1e30f;
    }
    float m = tv[0], s = 0.f, w[TOPK];
    #pragma unroll
    for (int k=0;k<TOPK;k++){ w[k] = expf(tv[k]-m); s += w[k]; }
    float inv = 1.f/s;
    #pragma unroll
    for (int k=0;k<TOPK;k++){
      tke[t*TOPK+k] = te[k];
      tkw[t*TOPK+k] = w[k]*inv;
      atomicAdd(&counts[te[k]], 1);
    }
  }
}

// ---------------- scatter (+ local scan; block 0 publishes offsets) ----------------
__global__ __launch_bounds__(256) void k_scatter(const int* __restrict__ tke,
    const float* __restrict__ tkw, const int* __restrict__ counts,
    int* __restrict__ offsets, int* __restrict__ cursors,
    int* __restrict__ ltok, float* __restrict__ lw){
  __shared__ int loff[NE+1];
  if (threadIdx.x == 0){
    int a = 0;
    for (int e=0;e<NE;e++){ loff[e] = a; a += counts[e]; }
    loff[NE] = a;
    if (blockIdx.x == 0){
      for (int e=0;e<=NE;e++) offsets[e] = loff[e];
    }
  }
  __syncthreads();
  int t = blockIdx.x*256 + threadIdx.x;
  #pragma unroll
  for (int k=0;k<TOPK;k++){
    int e = tke[t*TOPK+k];
    int p = atomicAdd(&cursors[e], 1);
    int r = loff[e] + p;
    ltok[r] = t;
    lw[r]   = tkw[t*TOPK+k];
  }
}

// ---------------- weight transpose+convert: grid-stride fat blocks ----------------
// src [R][C] fp32 per expert -> dst [C][R] bf16.  Tile: 64 R x 128 C.
__global__ __launch_bounds__(256) void k_wcvt(const float* __restrict__ src,
    u16* __restrict__ dst, int R, int C){
  int ntR = R >> 6, ntC = C >> 7;
  int ntiles = NE * ntR * ntC;
  __shared__ u16 t[64][136];
  int tid = threadIdx.x;
  for (int tile = blockIdx.x; tile < ntiles; tile += gridDim.x){
    int e   = tile / (ntR*ntC);
    int rem = tile % (ntR*ntC);
    int rt  = rem / ntC, ct = rem % ntC;
    const float* s = src + (size_t)e*R*C + (size_t)(rt*64)*C + ct*128;
    u16*         d = dst + (size_t)e*R*C + (size_t)(ct*128)*R + rt*64;
    // load+convert: 64x128 = 2048 float4; 256 thr x 8
    #pragma unroll
    for (int it=0; it<8; it++){
      int i  = it*256 + tid;
      int rr = i >> 5;            // 0..63
      int c4 = (i & 31) << 2;     // 0..124
      float4 v = *(const float4*)(s + (size_t)rr*C + c4);
      t[rr][c4+0] = f2bf(v.x);
      t[rr][c4+1] = f2bf(v.y);
      t[rr][c4+2] = f2bf(v.z);
      t[rr][c4+3] = f2bf(v.w);
    }
    __syncthreads();
    // store transposed: 128 cols x 8 x uint4(8 R-elems); 256 thr x 4
    #pragma unroll
    for (int it=0; it<4; it++){
      int i   = it*256 + tid;
      int cc  = i >> 3;           // 0..127
      int rr0 = (i & 7) << 3;     // 0..56
      uint4 o;
      o.x = (u32)t[rr0+0][cc] | ((u32)t[rr0+1][cc] << 16);
      o.y = (u32)t[rr0+2][cc] | ((u32)t[rr0+3][cc] << 16);
      o.z = (u32)t[rr0+4][cc] | ((u32)t[rr0+5][cc] << 16);
      o.w = (u32)t[rr0+6][cc] | ((u32)t[rr0+7][cc] << 16);
      *(uint4*)(d + (size_t)cc*R + rr0) = o;
    }
    __syncthreads();
  }
}

// ---------------- grouped GEMM1 + exact GELU -> hdn bf16 ----------------
// tile 128x128, BK=64, 4 waves x 64x64, 2-phase dbuf, XOR-swizzled LDS.
__global__ __launch_bounds__(256) void k_ffn1(
    const u16* __restrict__ xb, const u16* __restrict__ w1t,
    const float* __restrict__ b1,
    const int* __restrict__ counts, const int* __restrict__ offsets,
    const int* __restrict__ ltok, u16* __restrict__ hdn){
  int e = blockIdx.z;
  int cnt = counts[e];
  int row0 = blockIdx.y << 7;
  if (row0 >= cnt) return;
  int n0 = blockIdx.x << 7;
  int soff = offsets[e];
  const int* lt = ltok + soff;

  __shared__ u16 lA[2][128*64];
  __shared__ u16 lB[2][128*64];

  int tid = threadIdx.x, lane = tid & 63, wv = tid >> 6;
  int wr = (wv >> 1) << 6, wc = (wv & 1) << 6;
  int l15 = lane & 15, lkhi = (lane >> 4) << 3;

  f32x4 acc[4][4];
  #pragma unroll
  for (int m=0;m<4;m++){
    #pragma unroll
    for (int n=0;n<4;n++) acc[m][n] = (f32x4)0.f;
  }
  const u16* wBp = w1t + ((size_t)e*FFN + n0)*HID;

  size_t aoff[4], boff[4];
  #pragma unroll
  for (int it=0; it<4; it++){
    int idx = it*256 + tid;
    int row = idx >> 3;
    int kc  = ((idx & 7) ^ (row & 7)) << 3;
    int rc = row0 + row; if (rc > cnt-1) rc = cnt-1;
    aoff[it] = (size_t)lt[rc]*HID + kc;
    boff[it] = (size_t)row*HID + kc;
  }

  auto stage = [&](int buf, int k0v){
    #pragma unroll
    for (int it=0; it<4; it++){
      int idx = it*256 + tid;
      gload_lds16(xb  + aoff[it] + k0v, &lA[buf][idx<<3]);
      gload_lds16(wBp + boff[it] + k0v, &lB[buf][idx<<3]);
    }
  };

  stage(0, 0);
  __syncthreads();
  int cur = 0;
  for (int t=0; t<HID/64; ++t){
    if (t+1 < HID/64) stage(cur^1, (t+1)*64);
    #pragma unroll
    for (int kk=0; kk<64; kk+=32){
      bf16x8 af[4], bfv[4];
      #pragma unroll
      for (int m=0;m<4;m++){
        int ra = wr + m*16 + l15;
        af[m]  = *(const bf16x8*)&lA[cur][ra*64 + ((kk + lkhi) ^ ((ra&7)<<3))];
      }
      #pragma unroll
      for (int n=0;n<4;n++){
        int rb = wc + n*16 + l15;
        bfv[n] = *(const bf16x8*)&lB[cur][rb*64 + ((kk + lkhi) ^ ((rb&7)<<3))];
      }
      #pragma unroll
      for (int m=0;m<4;m++){
        #pragma unroll
        for (int n=0;n<4;n++)
          acc[m][n] = __builtin_amdgcn_mfma_f32_16x16x32_bf16(af[m], bfv[n], acc[m][n], 0,0,0);
      }
    }
    __syncthreads();
    cur ^= 1;
  }
  int rhi = (lane >> 4) << 2;
  #pragma unroll
  for (int m=0;m<4;m++){
    int rl = wr + m*16 + rhi;
    #pragma unroll
    for (int j=0;j<4;j++){
      int row = row0 + rl + j;
      if (row < cnt){
        size_t base = (size_t)(soff + row)*FFN;
        #pragma unroll
        for (int n=0;n<4;n++){
          int col = n0 + wc + n*16 + l15;
          float z = acc[m][n][j] + b1[(size_t)e*FFN + col];
          float g = 0.5f*z*(1.0f + erff(z*0.70710678118654752f));  // exact GELU
          hdn[base + col] = f2bf(g);
        }
      }
    }
  }
}

// ---------------- grouped GEMM2 -> weighted atomicAdd into out ----------------
__global__ __launch_bounds__(256) void k_ffn2(
    const u16* __restrict__ hdn, const u16* __restrict__ w2t,
    const float* __restrict__ b2,
    const int* __restrict__ counts, const int* __restrict__ offsets,
    const int* __restrict__ ltok, const float* __restrict__ lw,
    float* __restrict__ out){
  int e = blockIdx.z;
  int cnt = counts[e];
  int row0 = blockIdx.y << 7;
  if (row0 >= cnt) return;
  int n0 = blockIdx.x << 7;
  int soff = offsets[e];

  __shared__ u16 lA[2][128*64];
  __shared__ u16 lB[2][128*64];

  int tid = threadIdx.x, lane = tid & 63, wv = tid >> 6;
  int wr = (wv >> 1) << 6, wc = (wv & 1) << 6;
  int l15 = lane & 15, lkhi = (lane >> 4) << 3;

  f32x4 acc[4][4];
  #pragma unroll
  for (int m=0;m<4;m++){
    #pragma unroll
    for (int n=0;n<4;n++) acc[m][n] = (f32x4)0.f;
  }
  const u16* wBp = w2t + ((size_t)e*HID + n0)*FFN;

  size_t aoff[4], boff[4];
  #pragma unroll
  for (int it=0; it<4; it++){
    int idx = it*256 + tid;
    int row = idx >> 3;
    int kc  = ((idx & 7) ^ (row & 7)) << 3;
    int rc = row0 + row; if (rc > cnt-1) rc = cnt-1;
    aoff[it] = (size_t)(soff+rc)*FFN + kc;
    boff[it] = (size_t)row*FFN + kc;
  }

  auto stage = [&](int buf, int k0v){
    #pragma unroll
    for (int it=0; it<4; it++){
      int idx = it*256 + tid;
      gload_lds16(hdn + aoff[it] + k0v, &lA[buf][idx<<3]);
      gload_lds16(wBp + boff[it] + k0v, &lB[buf][idx<<3]);
    }
  };

  stage(0, 0);
  __syncthreads();
  int cur = 0;
  for (int t=0; t<FFN/64; ++t){
    if (t+1 < FFN/64) stage(cur^1, (t+1)*64);
    #pragma unroll
    for (int kk=0; kk<64; kk+=32){
      bf16x8 af[4], bfv[4];
      #pragma unroll
      for (int m=0;m<4;m++){
        int ra = wr + m*16 + l15;
        af[m]  = *(const bf16x8*)&lA[cur][ra*64 + ((kk + lkhi) ^ ((ra&7)<<3))];
      }
      #pragma unroll
      for (int n=0;n<4;n++){
        int rb = wc + n*16 + l15;
        bfv[n] = *(const bf16x8*)&lB[cur][rb*64 + ((kk + lkhi) ^ ((rb&7)<<3))];
      }
      #pragma unroll
      for (int m=0;m<4;m++){
        #pragma unroll
        for (int n=0;n<4;n++)
          acc[m][n] = __builtin_amdgcn_mfma_f32_16x16x32_bf16(af[m], bfv[n], acc[m][n], 0,0,0);
      }
    }
    __syncthreads();
    cur ^= 1;
  }
  int rhi = (lane >> 4) << 2;
  #pragma unroll
  for (int m=0;m<4;m++){
    int rl = wr + m*16 + rhi;
    #pragma unroll
    for (int j=0;j<4;j++){
      int row = row0 + rl + j;
      if (row < cnt){
        float sw = lw[soff+row];
        int tok  = ltok[soff+row];
        float* orow = out + (size_t)tok*HID;
        #pragma unroll
        for (int n=0;n<4;n++){
          int col = n0 + wc + n*16 + l15;
          atomicAdd(orow + col, sw*(acc[m][n][j] + b2[(size_t)e*HID + col]));
        }
      }
    }
  }
}

extern "C" void kernel_launch(void* const* d_in, const int* in_sizes, int n_in,
                              void* d_out, int out_size, void* d_ws, size_t ws_size,
                              hipStream_t stream){
  const float* x  = (const float*)d_in[0];
  const float* Wg = (const float*)d_in[1];
  const float* bg = (const float*)d_in[2];
  const float* W1 = (const float*)d_in[3];
  const float* b1 = (const float*)d_in[4];
  const float* W2 = (const float*)d_in[5];
  const float* b2 = (const float*)d_in[6];
  float* out = (float*)d_out;

  char* ws = (char*)d_ws;
  size_t off = 0;
  u16* SLOT_A = (u16*)(ws + off); off += (size_t)NE*FFN*HID*2;   // W1T, then W2T
  u16* XB  = (u16*)(ws + off); off += (size_t)NTOK*HID*2;
  u16* HDN = (u16*)(ws + off); off += (size_t)NPAIR*FFN*2;
  int*   LTOK = (int*)(ws + off);   off += (size_t)NPAIR*4;
  float* LW   = (float*)(ws + off); off += (size_t)NPAIR*4;
  int*   TKE  = (int*)(ws + off);   off += (size_t)NPAIR*4;
  float* TKW  = (float*)(ws + off); off += (size_t)NPAIR*4;
  int*   CTRL = (int*)(ws + off);   off += 256;
  int* counts  = CTRL;
  int* offsets = CTRL + 16;
  int* cursors = CTRL + 33;

  (void)hipMemsetAsync(CTRL, 0, 256, stream);
  (void)hipMemsetAsync(out, 0, (size_t)NTOK*HID*sizeof(float), stream);

  k_gating<<<NTOK/4, 256, 0, stream>>>(x, Wg, bg, counts, TKE, TKW, XB);
  k_scatter<<<NTOK/256, 256, 0, stream>>>(TKE, TKW, counts, offsets, cursors, LTOK, LW);
  // W1 -> SLOT_A, run GEMM1; then W2 -> SLOT_A (stream-serialized), run GEMM2.
  k_wcvt<<<2048, 256, 0, stream>>>(W1, SLOT_A, HID, FFN);
  k_ffn1<<<dim3(FFN/128, NTOK/128, NE), 256, 0, stream>>>(XB, SLOT_A, b1, counts, offsets, LTOK, HDN);
  k_wcvt<<<2048, 256, 0, stream>>>(W2, SLOT_A, FFN, HID);
  k_ffn2<<<dim3(HID/128, NTOK/128, NE), 256, 0, stream>>>(HDN, SLOT_A, b2, counts, offsets, LTOK, LW, out);
}

// Round 14
// 2247.927 us; speedup vs baseline: 1.0359x; 1.0359x over previous
//
#include <hip/hip_runtime.h>
#include <hip/hip_bf16.h>

// MoE top-4 of 16 experts, T=8192 tokens, HID=1024, FFN=4096.
// R7:  XOR-swizzled LDS (conflicts 1.03e8 -> 0, verified).
// R9:  2-phase double-buffered K-loop (+3%).
// R10: non-GEMM overhaul (null -> non-GEMM was never the sink).
// R12: GEMM geometry 128x128/4-wave -> 256x256/8-wave (m248 "2ph 256^2"
//      grouped-GEMM config, 655-682 TF proven). Sync structure unchanged.
// ws layout (peak ~400.5 MiB):
//   SLOT_A bf16 [E][N][K]   134217728 B  (W1T for ffn1, then W2T for ffn2)
//   XB  bf16 [T][HID]        16777216 B
//   HDN bf16 [4T][FFN]      268435456 B
//   LTOK/LW/TKE/TKW         4*131072  B
//   CTRL ints               256 B

#define HID 1024
#define FFN 4096
#define NE 16
#define TOPK 4
#define NTOK 8192
#define NPAIR (NTOK*TOPK)

typedef __attribute__((ext_vector_type(4))) float f32x4;
typedef __attribute__((ext_vector_type(8))) short bf16x8;
typedef unsigned short u16;
typedef unsigned int u32;

__device__ __forceinline__ u16 f2bf(float f){
  u32 u = __float_as_uint(f);
  u32 r = (u + 0x7fffu + ((u >> 16) & 1u)) >> 16;   // RNE
  return (u16)r;
}

__device__ __forceinline__ void gload_lds16(const void* g, void* l){
  __builtin_amdgcn_global_load_lds((const __attribute__((address_space(1))) void*)g,
                                   (__attribute__((address_space(3))) void*)l, 16, 0, 0);
}

// ---------------- gating (+ fused x->bf16 convert): one wave per token ----------------
__global__ __launch_bounds__(256) void k_gating(const float* __restrict__ x,
    const float* __restrict__ Wg, const float* __restrict__ bg,
    int* __restrict__ counts, int* __restrict__ tke, float* __restrict__ tkw,
    u16* __restrict__ xb){
  int t    = (blockIdx.x << 2) + (threadIdx.x >> 6);
  int lane = threadIdx.x & 63;
  const float* xr = x + (size_t)t*HID + lane*16;
  const float4* p = (const float4*)xr;
  float4 va = p[0], vb = p[1], vc = p[2], vd = p[3];
  float xv[16] = {va.x,va.y,va.z,va.w, vb.x,vb.y,vb.z,vb.w,
                  vc.x,vc.y,vc.z,vc.w, vd.x,vd.y,vd.z,vd.w};
  float acc[NE];
  #pragma unroll
  for (int e=0;e<NE;e++) acc[e] = 0.f;
  #pragma unroll
  for (int j=0;j<16;j++){
    const float* wr = Wg + (size_t)(lane*16 + j)*NE;
    #pragma unroll
    for (int e=0;e<NE;e++) acc[e] += xv[j] * wr[e];
  }
  uint4 o0, o1;
  o0.x = (u32)f2bf(xv[0])  | ((u32)f2bf(xv[1])  << 16);
  o0.y = (u32)f2bf(xv[2])  | ((u32)f2bf(xv[3])  << 16);
  o0.z = (u32)f2bf(xv[4])  | ((u32)f2bf(xv[5])  << 16);
  o0.w = (u32)f2bf(xv[6])  | ((u32)f2bf(xv[7])  << 16);
  o1.x = (u32)f2bf(xv[8])  | ((u32)f2bf(xv[9])  << 16);
  o1.y = (u32)f2bf(xv[10]) | ((u32)f2bf(xv[11]) << 16);
  o1.z = (u32)f2bf(xv[12]) | ((u32)f2bf(xv[13]) << 16);
  o1.w = (u32)f2bf(xv[14]) | ((u32)f2bf(xv[15]) << 16);
  u16* xbr = xb + (size_t)t*HID + lane*16;
  *(uint4*)xbr       = o0;
  *(uint4*)(xbr + 8) = o1;

  #pragma unroll
  for (int off=32; off; off>>=1){
    #pragma unroll
    for (int e=0;e<NE;e++) acc[e] += __shfl_xor(acc[e], off);
  }
  if (lane == 0){
    #pragma unroll
    for (int e=0;e<NE;e++) acc[e] += bg[e];
    int te[TOPK]; float tv[TOPK];
    #pragma unroll
    for (int k=0;k<TOPK;k++){
      int bi = 0; float bv = -1e30f;
      #pragma unroll
      for (int e=0;e<NE;e++) if (acc[e] > bv){ bv = acc[e]; bi = e; }
      te[k] = bi; tv[k] = bv; acc[bi] = -1e30f;
    }
    float m = tv[0], s = 0.f, w[TOPK];
    #pragma unroll
    for (int k=0;k<TOPK;k++){ w[k] = expf(tv[k]-m); s += w[k]; }
    float inv = 1.f/s;
    #pragma unroll
    for (int k=0;k<TOPK;k++){
      tke[t*TOPK+k] = te[k];
      tkw[t*TOPK+k] = w[k]*inv;
      atomicAdd(&counts[te[k]], 1);
    }
  }
}

// ---------------- scatter (+ local scan; block 0 publishes offsets) ----------------
__global__ __launch_bounds__(256) void k_scatter(const int* __restrict__ tke,
    const float* __restrict__ tkw, const int* __restrict__ counts,
    int* __restrict__ offsets, int* __restrict__ cursors,
    int* __restrict__ ltok, float* __restrict__ lw){
  __shared__ int loff[NE+1];
  if (threadIdx.x == 0){
    int a = 0;
    for (int e=0;e<NE;e++){ loff[e] = a; a += counts[e]; }
    loff[NE] = a;
    if (blockIdx.x == 0){
      for (int e=0;e<=NE;e++) offsets[e] = loff[e];
    }
  }
  __syncthreads();
  int t = blockIdx.x*256 + threadIdx.x;
  #pragma unroll
  for (int k=0;k<TOPK;k++){
    int e = tke[t*TOPK+k];
    int p = atomicAdd(&cursors[e], 1);
    int r = loff[e] + p;
    ltok[r] = t;
    lw[r]   = tkw[t*TOPK+k];
  }
}

// ---------------- weight transpose+convert: grid-stride fat blocks ----------------
__global__ __launch_bounds__(256) void k_wcvt(const float* __restrict__ src,
    u16* __restrict__ dst, int R, int C){
  int ntR = R >> 6, ntC = C >> 7;
  int ntiles = NE * ntR * ntC;
  __shared__ u16 t[64][136];
  int tid = threadIdx.x;
  for (int tile = blockIdx.x; tile < ntiles; tile += gridDim.x){
    int e   = tile / (ntR*ntC);
    int rem = tile % (ntR*ntC);
    int rt  = rem / ntC, ct = rem % ntC;
    const float* s = src + (size_t)e*R*C + (size_t)(rt*64)*C + ct*128;
    u16*         d = dst + (size_t)e*R*C + (size_t)(ct*128)*R + rt*64;
    #pragma unroll
    for (int it=0; it<8; it++){
      int i  = it*256 + tid;
      int rr = i >> 5;
      int c4 = (i & 31) << 2;
      float4 v = *(const float4*)(s + (size_t)rr*C + c4);
      t[rr][c4+0] = f2bf(v.x);
      t[rr][c4+1] = f2bf(v.y);
      t[rr][c4+2] = f2bf(v.z);
      t[rr][c4+3] = f2bf(v.w);
    }
    __syncthreads();
    #pragma unroll
    for (int it=0; it<4; it++){
      int i   = it*256 + tid;
      int cc  = i >> 3;
      int rr0 = (i & 7) << 3;
      uint4 o;
      o.x = (u32)t[rr0+0][cc] | ((u32)t[rr0+1][cc] << 16);
      o.y = (u32)t[rr0+2][cc] | ((u32)t[rr0+3][cc] << 16);
      o.z = (u32)t[rr0+4][cc] | ((u32)t[rr0+5][cc] << 16);
      o.w = (u32)t[rr0+6][cc] | ((u32)t[rr0+7][cc] << 16);
      *(uint4*)(d + (size_t)cc*R + rr0) = o;
    }
    __syncthreads();
  }
}

// ---------------- grouped GEMM1 + exact GELU -> hdn bf16 ----------------
// tile 256x256, BK=64, 8 waves (2M x 4N, 128x64 each), 2-phase dbuf,
// XOR-swizzled LDS (128 KiB).
__global__ __launch_bounds__(512, 2) void k_ffn1(
    const u16* __restrict__ xb, const u16* __restrict__ w1t,
    const float* __restrict__ b1,
    const int* __restrict__ counts, const int* __restrict__ offsets,
    const int* __restrict__ ltok, u16* __restrict__ hdn){
  int e = blockIdx.z;
  int cnt = counts[e];
  int row0 = blockIdx.y << 8;
  if (row0 >= cnt) return;
  int n0 = blockIdx.x << 8;
  int soff = offsets[e];
  const int* lt = ltok + soff;

  __shared__ u16 lA[2][256*64];
  __shared__ u16 lB[2][256*64];

  int tid = threadIdx.x, lane = tid & 63, wv = tid >> 6;
  int wr = (wv >> 2) << 7;          // 0 or 128
  int wc = (wv & 3) << 6;           // 0,64,128,192
  int l15 = lane & 15, lkhi = (lane >> 4) << 3;

  f32x4 acc[8][4];
  #pragma unroll
  for (int m=0;m<8;m++){
    #pragma unroll
    for (int n=0;n<4;n++) acc[m][n] = (f32x4)0.f;
  }
  const u16* wBp = w1t + ((size_t)e*FFN + n0)*HID;

  // per-thread staging offsets (k0-invariant); 4 chunks A + 4 chunks B
  u32 aoff[4], boff[4];
  #pragma unroll
  for (int it=0; it<4; it++){
    int cidx = it*512 + tid;            // [0,2048)
    int row  = cidx >> 3;               // [0,256)
    int kc   = ((cidx & 7) ^ (row & 7)) << 3;
    int rc = row0 + row; if (rc > cnt-1) rc = cnt-1;
    aoff[it] = (u32)lt[rc]*HID + kc;
    boff[it] = (u32)row*HID + kc;
  }

  auto stage = [&](int buf, int k0v){
    #pragma unroll
    for (int it=0; it<4; it++){
      int cidx = it*512 + tid;
      gload_lds16(xb  + aoff[it] + k0v, &lA[buf][cidx<<3]);
      gload_lds16(wBp + boff[it] + k0v, &lB[buf][cidx<<3]);
    }
  };

  stage(0, 0);
  __syncthreads();
  int cur = 0;
  for (int t=0; t<HID/64; ++t){
    if (t+1 < HID/64) stage(cur^1, (t+1)*64);
    #pragma unroll
    for (int kk=0; kk<64; kk+=32){
      bf16x8 af[8], bfv[4];
      #pragma unroll
      for (int m=0;m<8;m++){
        int ra = wr + m*16 + l15;
        af[m]  = *(const bf16x8*)&lA[cur][ra*64 + ((kk + lkhi) ^ ((ra&7)<<3))];
      }
      #pragma unroll
      for (int n=0;n<4;n++){
        int rb = wc + n*16 + l15;
        bfv[n] = *(const bf16x8*)&lB[cur][rb*64 + ((kk + lkhi) ^ ((rb&7)<<3))];
      }
      #pragma unroll
      for (int m=0;m<8;m++){
        #pragma unroll
        for (int n=0;n<4;n++)
          acc[m][n] = __builtin_amdgcn_mfma_f32_16x16x32_bf16(af[m], bfv[n], acc[m][n], 0,0,0);
      }
    }
    __syncthreads();
    cur ^= 1;
  }
  int rhi = (lane >> 4) << 2;
  #pragma unroll
  for (int m=0;m<8;m++){
    int rl = wr + m*16 + rhi;
    #pragma unroll
    for (int j=0;j<4;j++){
      int row = row0 + rl + j;
      if (row < cnt){
        size_t base = (size_t)(soff + row)*FFN;
        #pragma unroll
        for (int n=0;n<4;n++){
          int col = n0 + wc + n*16 + l15;
          float z = acc[m][n][j] + b1[(size_t)e*FFN + col];
          float g = 0.5f*z*(1.0f + erff(z*0.70710678118654752f));  // exact GELU
          hdn[base + col] = f2bf(g);
        }
      }
    }
  }
}

// ---------------- grouped GEMM2 -> weighted atomicAdd into out ----------------
// tile 256x256, BK=64, 8 waves, 2-phase dbuf, XOR-swizzled LDS.
__global__ __launch_bounds__(512, 2) void k_ffn2(
    const u16* __restrict__ hdn, const u16* __restrict__ w2t,
    const float* __restrict__ b2,
    const int* __restrict__ counts, const int* __restrict__ offsets,
    const int* __restrict__ ltok, const float* __restrict__ lw,
    float* __restrict__ out){
  int e = blockIdx.z;
  int cnt = counts[e];
  int row0 = blockIdx.y << 8;
  if (row0 >= cnt) return;
  int n0 = blockIdx.x << 8;
  int soff = offsets[e];

  __shared__ u16 lA[2][256*64];
  __shared__ u16 lB[2][256*64];

  int tid = threadIdx.x, lane = tid & 63, wv = tid >> 6;
  int wr = (wv >> 2) << 7;
  int wc = (wv & 3) << 6;
  int l15 = lane & 15, lkhi = (lane >> 4) << 3;

  f32x4 acc[8][4];
  #pragma unroll
  for (int m=0;m<8;m++){
    #pragma unroll
    for (int n=0;n<4;n++) acc[m][n] = (f32x4)0.f;
  }
  const u16* wBp = w2t + ((size_t)e*HID + n0)*FFN;

  u32 aoff[4], boff[4];
  #pragma unroll
  for (int it=0; it<4; it++){
    int cidx = it*512 + tid;
    int row  = cidx >> 3;
    int kc   = ((cidx & 7) ^ (row & 7)) << 3;
    int rc = row0 + row; if (rc > cnt-1) rc = cnt-1;
    aoff[it] = (u32)(soff+rc)*FFN + kc;
    boff[it] = (u32)row*FFN + kc;
  }

  auto stage = [&](int buf, int k0v){
    #pragma unroll
    for (int it=0; it<4; it++){
      int cidx = it*512 + tid;
      gload_lds16(hdn + aoff[it] + k0v, &lA[buf][cidx<<3]);
      gload_lds16(wBp + boff[it] + k0v, &lB[buf][cidx<<3]);
    }
  };

  stage(0, 0);
  __syncthreads();
  int cur = 0;
  for (int t=0; t<FFN/64; ++t){
    if (t+1 < FFN/64) stage(cur^1, (t+1)*64);
    #pragma unroll
    for (int kk=0; kk<64; kk+=32){
      bf16x8 af[8], bfv[4];
      #pragma unroll
      for (int m=0;m<8;m++){
        int ra = wr + m*16 + l15;
        af[m]  = *(const bf16x8*)&lA[cur][ra*64 + ((kk + lkhi) ^ ((ra&7)<<3))];
      }
      #pragma unroll
      for (int n=0;n<4;n++){
        int rb = wc + n*16 + l15;
        bfv[n] = *(const bf16x8*)&lB[cur][rb*64 + ((kk + lkhi) ^ ((rb&7)<<3))];
      }
      #pragma unroll
      for (int m=0;m<8;m++){
        #pragma unroll
        for (int n=0;n<4;n++)
          acc[m][n] = __builtin_amdgcn_mfma_f32_16x16x32_bf16(af[m], bfv[n], acc[m][n], 0,0,0);
      }
    }
    __syncthreads();
    cur ^= 1;
  }
  int rhi = (lane >> 4) << 2;
  #pragma unroll
  for (int m=0;m<8;m++){
    int rl = wr + m*16 + rhi;
    #pragma unroll
    for (int j=0;j<4;j++){
      int row = row0 + rl + j;
      if (row < cnt){
        float sw = lw[soff+row];
        int tok  = ltok[soff+row];
        float* orow = out + (size_t)tok*HID;
        #pragma unroll
        for (int n=0;n<4;n++){
          int col = n0 + wc + n*16 + l15;
          atomicAdd(orow + col, sw*(acc[m][n][j] + b2[(size_t)e*HID + col]));
        }
      }
    }
  }
}

extern "C" void kernel_launch(void* const* d_in, const int* in_sizes, int n_in,
                              void* d_out, int out_size, void* d_ws, size_t ws_size,
                              hipStream_t stream){
  const float* x  = (const float*)d_in[0];
  const float* Wg = (const float*)d_in[1];
  const float* bg = (const float*)d_in[2];
  const float* W1 = (const float*)d_in[3];
  const float* b1 = (const float*)d_in[4];
  const float* W2 = (const float*)d_in[5];
  const float* b2 = (const float*)d_in[6];
  float* out = (float*)d_out;

  char* ws = (char*)d_ws;
  size_t off = 0;
  u16* SLOT_A = (u16*)(ws + off); off += (size_t)NE*FFN*HID*2;   // W1T, then W2T
  u16* XB  = (u16*)(ws + off); off += (size_t)NTOK*HID*2;
  u16* HDN = (u16*)(ws + off); off += (size_t)NPAIR*FFN*2;
  int*   LTOK = (int*)(ws + off);   off += (size_t)NPAIR*4;
  float* LW   = (float*)(ws + off); off += (size_t)NPAIR*4;
  int*   TKE  = (int*)(ws + off);   off += (size_t)NPAIR*4;
  float* TKW  = (float*)(ws + off); off += (size_t)NPAIR*4;
  int*   CTRL = (int*)(ws + off);   off += 256;
  int* counts  = CTRL;
  int* offsets = CTRL + 16;
  int* cursors = CTRL + 33;

  (void)hipMemsetAsync(CTRL, 0, 256, stream);
  (void)hipMemsetAsync(out, 0, (size_t)NTOK*HID*sizeof(float), stream);

  k_gating<<<NTOK/4, 256, 0, stream>>>(x, Wg, bg, counts, TKE, TKW, XB);
  k_scatter<<<NTOK/256, 256, 0, stream>>>(TKE, TKW, counts, offsets, cursors, LTOK, LW);
  k_wcvt<<<2048, 256, 0, stream>>>(W1, SLOT_A, HID, FFN);
  k_ffn1<<<dim3(FFN/256, NTOK/256, NE), 512, 0, stream>>>(XB, SLOT_A, b1, counts, offsets, LTOK, HDN);
  k_wcvt<<<2048, 256, 0, stream>>>(W2, SLOT_A, FFN, HID);
  k_ffn2<<<dim3(HID/256, NTOK/256, NE), 512, 0, stream>>>(HDN, SLOT_A, b2, counts, offsets, LTOK, LW, out);
}

// Round 15
// 2193.280 us; speedup vs baseline: 1.0617x; 1.0249x over previous
//
#include <hip/hip_runtime.h>
#include <hip/hip_bf16.h>

// MoE top-4 of 16 experts, T=8192 tokens, HID=1024, FFN=4096.
// R7:  XOR-swizzled LDS (conflicts 1.03e8 -> 0, verified).
// R9:  2-phase double-buffered K-loop.
// R12: 256x256/8-wave geometry (VALUBusy 45->8; +80us).
// R14: persistent-block grouped GEMM — grid=256 (1 block/CU), device-side
//      work-list decode from counts[]; kills idle-block churn (Occupancy 17%).
// ws layout (peak ~400.5 MiB):
//   SLOT_A bf16 [E][N][K]   134217728 B  (W1T for ffn1, then W2T for ffn2)
//   XB  bf16 [T][HID]        16777216 B
//   HDN bf16 [4T][FFN]      268435456 B
//   LTOK/LW/TKE/TKW         4*131072  B
//   CTRL ints               256 B

#define HID 1024
#define FFN 4096
#define NE 16
#define TOPK 4
#define NTOK 8192
#define NPAIR (NTOK*TOPK)

typedef __attribute__((ext_vector_type(4))) float f32x4;
typedef __attribute__((ext_vector_type(8))) short bf16x8;
typedef unsigned short u16;
typedef unsigned int u32;

__device__ __forceinline__ u16 f2bf(float f){
  u32 u = __float_as_uint(f);
  u32 r = (u + 0x7fffu + ((u >> 16) & 1u)) >> 16;   // RNE
  return (u16)r;
}

__device__ __forceinline__ void gload_lds16(const void* g, void* l){
  __builtin_amdgcn_global_load_lds((const __attribute__((address_space(1))) void*)g,
                                   (__attribute__((address_space(3))) void*)l, 16, 0, 0);
}

// ---------------- gating (+ fused x->bf16 convert): one wave per token ----------------
__global__ __launch_bounds__(256) void k_gating(const float* __restrict__ x,
    const float* __restrict__ Wg, const float* __restrict__ bg,
    int* __restrict__ counts, int* __restrict__ tke, float* __restrict__ tkw,
    u16* __restrict__ xb){
  int t    = (blockIdx.x << 2) + (threadIdx.x >> 6);
  int lane = threadIdx.x & 63;
  const float* xr = x + (size_t)t*HID + lane*16;
  const float4* p = (const float4*)xr;
  float4 va = p[0], vb = p[1], vc = p[2], vd = p[3];
  float xv[16] = {va.x,va.y,va.z,va.w, vb.x,vb.y,vb.z,vb.w,
                  vc.x,vc.y,vc.z,vc.w, vd.x,vd.y,vd.z,vd.w};
  float acc[NE];
  #pragma unroll
  for (int e=0;e<NE;e++) acc[e] = 0.f;
  #pragma unroll
  for (int j=0;j<16;j++){
    const float* wr = Wg + (size_t)(lane*16 + j)*NE;
    #pragma unroll
    for (int e=0;e<NE;e++) acc[e] += xv[j] * wr[e];
  }
  uint4 o0, o1;
  o0.x = (u32)f2bf(xv[0])  | ((u32)f2bf(xv[1])  << 16);
  o0.y = (u32)f2bf(xv[2])  | ((u32)f2bf(xv[3])  << 16);
  o0.z = (u32)f2bf(xv[4])  | ((u32)f2bf(xv[5])  << 16);
  o0.w = (u32)f2bf(xv[6])  | ((u32)f2bf(xv[7])  << 16);
  o1.x = (u32)f2bf(xv[8])  | ((u32)f2bf(xv[9])  << 16);
  o1.y = (u32)f2bf(xv[10]) | ((u32)f2bf(xv[11]) << 16);
  o1.z = (u32)f2bf(xv[12]) | ((u32)f2bf(xv[13]) << 16);
  o1.w = (u32)f2bf(xv[14]) | ((u32)f2bf(xv[15]) << 16);
  u16* xbr = xb + (size_t)t*HID + lane*16;
  *(uint4*)xbr       = o0;
  *(uint4*)(xbr + 8) = o1;

  #pragma unroll
  for (int off=32; off; off>>=1){
    #pragma unroll
    for (int e=0;e<NE;e++) acc[e] += __shfl_xor(acc[e], off);
  }
  if (lane == 0){
    #pragma unroll
    for (int e=0;e<NE;e++) acc[e] += bg[e];
    int te[TOPK]; float tv[TOPK];
    #pragma unroll
    for (int k=0;k<TOPK;k++){
      int bi = 0; float bv = -1e30f;
      #pragma unroll
      for (int e=0;e<NE;e++) if (acc[e] > bv){ bv = acc[e]; bi = e; }
      te[k] = bi; tv[k] = bv; acc[bi] = -1e30f;
    }
    float m = tv[0], s = 0.f, w[TOPK];
    #pragma unroll
    for (int k=0;k<TOPK;k++){ w[k] = expf(tv[k]-m); s += w[k]; }
    float inv = 1.f/s;
    #pragma unroll
    for (int k=0;k<TOPK;k++){
      tke[t*TOPK+k] = te[k];
      tkw[t*TOPK+k] = w[k]*inv;
      atomicAdd(&counts[te[k]], 1);
    }
  }
}

// ---------------- scatter (+ local scan; block 0 publishes offsets) ----------------
__global__ __launch_bounds__(256) void k_scatter(const int* __restrict__ tke,
    const float* __restrict__ tkw, const int* __restrict__ counts,
    int* __restrict__ offsets, int* __restrict__ cursors,
    int* __restrict__ ltok, float* __restrict__ lw){
  __shared__ int loff[NE+1];
  if (threadIdx.x == 0){
    int a = 0;
    for (int e=0;e<NE;e++){ loff[e] = a; a += counts[e]; }
    loff[NE] = a;
    if (blockIdx.x == 0){
      for (int e=0;e<=NE;e++) offsets[e] = loff[e];
    }
  }
  __syncthreads();
  int t = blockIdx.x*256 + threadIdx.x;
  #pragma unroll
  for (int k=0;k<TOPK;k++){
    int e = tke[t*TOPK+k];
    int p = atomicAdd(&cursors[e], 1);
    int r = loff[e] + p;
    ltok[r] = t;
    lw[r]   = tkw[t*TOPK+k];
  }
}

// ---------------- weight transpose+convert: grid-stride fat blocks ----------------
__global__ __launch_bounds__(256) void k_wcvt(const float* __restrict__ src,
    u16* __restrict__ dst, int R, int C){
  int ntR = R >> 6, ntC = C >> 7;
  int ntiles = NE * ntR * ntC;
  __shared__ u16 t[64][136];
  int tid = threadIdx.x;
  for (int tile = blockIdx.x; tile < ntiles; tile += gridDim.x){
    int e   = tile / (ntR*ntC);
    int rem = tile % (ntR*ntC);
    int rt  = rem / ntC, ct = rem % ntC;
    const float* s = src + (size_t)e*R*C + (size_t)(rt*64)*C + ct*128;
    u16*         d = dst + (size_t)e*R*C + (size_t)(ct*128)*R + rt*64;
    #pragma unroll
    for (int it=0; it<8; it++){
      int i  = it*256 + tid;
      int rr = i >> 5;
      int c4 = (i & 31) << 2;
      float4 v = *(const float4*)(s + (size_t)rr*C + c4);
      t[rr][c4+0] = f2bf(v.x);
      t[rr][c4+1] = f2bf(v.y);
      t[rr][c4+2] = f2bf(v.z);
      t[rr][c4+3] = f2bf(v.w);
    }
    __syncthreads();
    #pragma unroll
    for (int it=0; it<4; it++){
      int i   = it*256 + tid;
      int cc  = i >> 3;
      int rr0 = (i & 7) << 3;
      uint4 o;
      o.x = (u32)t[rr0+0][cc] | ((u32)t[rr0+1][cc] << 16);
      o.y = (u32)t[rr0+2][cc] | ((u32)t[rr0+3][cc] << 16);
      o.z = (u32)t[rr0+4][cc] | ((u32)t[rr0+5][cc] << 16);
      o.w = (u32)t[rr0+6][cc] | ((u32)t[rr0+7][cc] << 16);
      *(uint4*)(d + (size_t)cc*R + rr0) = o;
    }
    __syncthreads();
  }
}

// ---------------- persistent grouped GEMM1 + exact GELU -> hdn bf16 ----------------
// grid = 256 (1 block/CU); items = (e, row-tile, n-tile) decoded from counts.
// Per item: tile 256x256, BK=64, 8 waves, 2-phase dbuf, XOR-swizzled LDS.
__global__ __launch_bounds__(512, 2) void k_ffn1(
    const u16* __restrict__ xb, const u16* __restrict__ w1t,
    const float* __restrict__ b1,
    const int* __restrict__ counts, const int* __restrict__ offsets,
    const int* __restrict__ ltok, u16* __restrict__ hdn){
  __shared__ u16 lA[2][256*64];
  __shared__ u16 lB[2][256*64];

  int tid = threadIdx.x, lane = tid & 63, wv = tid >> 6;
  int wr = (wv >> 2) << 7;
  int wc = (wv & 3) << 6;
  int l15 = lane & 15, lkhi = (lane >> 4) << 3;
  int rhi = (lane >> 4) << 2;

  // work-list prefix: pref[e] = items before expert e; item = rt*NTN + nt
  const int NTN = FFN >> 8;               // 16 n-tiles
  int pref[NE+1];
  {
    int a = 0;
    #pragma unroll
    for (int e=0;e<NE;e++){ pref[e] = a; a += ((counts[e] + 255) >> 8) * NTN; }
    pref[NE] = a;
  }
  int tot = pref[NE];

  for (int item = blockIdx.x; item < tot; item += gridDim.x){
    int e = 0;
    #pragma unroll
    for (int q=0;q<NE;q++) if (item >= pref[q+1]) e = q+1;
    int loc = item - pref[e];
    int rt = loc / NTN, nt = loc % NTN;
    int cnt = counts[e];
    int row0 = rt << 8, n0 = nt << 8;
    int soff = offsets[e];
    const int* lt = ltok + soff;
    const u16* wBp = w1t + ((size_t)e*FFN + n0)*HID;

    f32x4 acc[8][4];
    #pragma unroll
    for (int m=0;m<8;m++){
      #pragma unroll
      for (int n=0;n<4;n++) acc[m][n] = (f32x4)0.f;
    }

    u32 aoff[4], boff[4];
    #pragma unroll
    for (int it=0; it<4; it++){
      int cidx = it*512 + tid;
      int row  = cidx >> 3;
      int kc   = ((cidx & 7) ^ (row & 7)) << 3;
      int rc = row0 + row; if (rc > cnt-1) rc = cnt-1;
      aoff[it] = (u32)lt[rc]*HID + kc;
      boff[it] = (u32)row*HID + kc;
    }

    auto stage = [&](int buf, int k0v){
      #pragma unroll
      for (int it=0; it<4; it++){
        int cidx = it*512 + tid;
        gload_lds16(xb  + aoff[it] + k0v, &lA[buf][cidx<<3]);
        gload_lds16(wBp + boff[it] + k0v, &lB[buf][cidx<<3]);
      }
    };

    stage(0, 0);
    __syncthreads();
    int cur = 0;
    for (int t=0; t<HID/64; ++t){
      if (t+1 < HID/64) stage(cur^1, (t+1)*64);
      #pragma unroll
      for (int kk=0; kk<64; kk+=32){
        bf16x8 af[8], bfv[4];
        #pragma unroll
        for (int m=0;m<8;m++){
          int ra = wr + m*16 + l15;
          af[m]  = *(const bf16x8*)&lA[cur][ra*64 + ((kk + lkhi) ^ ((ra&7)<<3))];
        }
        #pragma unroll
        for (int n=0;n<4;n++){
          int rb = wc + n*16 + l15;
          bfv[n] = *(const bf16x8*)&lB[cur][rb*64 + ((kk + lkhi) ^ ((rb&7)<<3))];
        }
        #pragma unroll
        for (int m=0;m<8;m++){
          #pragma unroll
          for (int n=0;n<4;n++)
            acc[m][n] = __builtin_amdgcn_mfma_f32_16x16x32_bf16(af[m], bfv[n], acc[m][n], 0,0,0);
        }
      }
      __syncthreads();
      cur ^= 1;
    }
    #pragma unroll
    for (int m=0;m<8;m++){
      int rl = wr + m*16 + rhi;
      #pragma unroll
      for (int j=0;j<4;j++){
        int row = row0 + rl + j;
        if (row < cnt){
          size_t base = (size_t)(soff + row)*FFN;
          #pragma unroll
          for (int n=0;n<4;n++){
            int col = n0 + wc + n*16 + l15;
            float z = acc[m][n][j] + b1[(size_t)e*FFN + col];
            float g = 0.5f*z*(1.0f + erff(z*0.70710678118654752f));  // exact GELU
            hdn[base + col] = f2bf(g);
          }
        }
      }
    }
    // all LDS reads for this item are behind the final k-loop barrier; next
    // item's stage may begin immediately (prologue barrier follows it).
  }
}

// ---------------- persistent grouped GEMM2 -> weighted atomicAdd into out ----------------
__global__ __launch_bounds__(512, 2) void k_ffn2(
    const u16* __restrict__ hdn, const u16* __restrict__ w2t,
    const float* __restrict__ b2,
    const int* __restrict__ counts, const int* __restrict__ offsets,
    const int* __restrict__ ltok, const float* __restrict__ lw,
    float* __restrict__ out){
  __shared__ u16 lA[2][256*64];
  __shared__ u16 lB[2][256*64];

  int tid = threadIdx.x, lane = tid & 63, wv = tid >> 6;
  int wr = (wv >> 2) << 7;
  int wc = (wv & 3) << 6;
  int l15 = lane & 15, lkhi = (lane >> 4) << 3;
  int rhi = (lane >> 4) << 2;

  const int NTN = HID >> 8;               // 4 n-tiles
  int pref[NE+1];
  {
    int a = 0;
    #pragma unroll
    for (int e=0;e<NE;e++){ pref[e] = a; a += ((counts[e] + 255) >> 8) * NTN; }
    pref[NE] = a;
  }
  int tot = pref[NE];

  for (int item = blockIdx.x; item < tot; item += gridDim.x){
    int e = 0;
    #pragma unroll
    for (int q=0;q<NE;q++) if (item >= pref[q+1]) e = q+1;
    int loc = item - pref[e];
    int rt = loc / NTN, nt = loc % NTN;
    int cnt = counts[e];
    int row0 = rt << 8, n0 = nt << 8;
    int soff = offsets[e];
    const u16* wBp = w2t + ((size_t)e*HID + n0)*FFN;

    f32x4 acc[8][4];
    #pragma unroll
    for (int m=0;m<8;m++){
      #pragma unroll
      for (int n=0;n<4;n++) acc[m][n] = (f32x4)0.f;
    }

    u32 aoff[4], boff[4];
    #pragma unroll
    for (int it=0; it<4; it++){
      int cidx = it*512 + tid;
      int row  = cidx >> 3;
      int kc   = ((cidx & 7) ^ (row & 7)) << 3;
      int rc = row0 + row; if (rc > cnt-1) rc = cnt-1;
      aoff[it] = (u32)(soff+rc)*FFN + kc;
      boff[it] = (u32)row*FFN + kc;
    }

    auto stage = [&](int buf, int k0v){
      #pragma unroll
      for (int it=0; it<4; it++){
        int cidx = it*512 + tid;
        gload_lds16(hdn + aoff[it] + k0v, &lA[buf][cidx<<3]);
        gload_lds16(wBp + boff[it] + k0v, &lB[buf][cidx<<3]);
      }
    };

    stage(0, 0);
    __syncthreads();
    int cur = 0;
    for (int t=0; t<FFN/64; ++t){
      if (t+1 < FFN/64) stage(cur^1, (t+1)*64);
      #pragma unroll
      for (int kk=0; kk<64; kk+=32){
        bf16x8 af[8], bfv[4];
        #pragma unroll
        for (int m=0;m<8;m++){
          int ra = wr + m*16 + l15;
          af[m]  = *(const bf16x8*)&lA[cur][ra*64 + ((kk + lkhi) ^ ((ra&7)<<3))];
        }
        #pragma unroll
        for (int n=0;n<4;n++){
          int rb = wc + n*16 + l15;
          bfv[n] = *(const bf16x8*)&lB[cur][rb*64 + ((kk + lkhi) ^ ((rb&7)<<3))];
        }
        #pragma unroll
        for (int m=0;m<8;m++){
          #pragma unroll
          for (int n=0;n<4;n++)
            acc[m][n] = __builtin_amdgcn_mfma_f32_16x16x32_bf16(af[m], bfv[n], acc[m][n], 0,0,0);
        }
      }
      __syncthreads();
      cur ^= 1;
    }
    #pragma unroll
    for (int m=0;m<8;m++){
      int rl = wr + m*16 + rhi;
      #pragma unroll
      for (int j=0;j<4;j++){
        int row = row0 + rl + j;
        if (row < cnt){
          float sw = lw[soff+row];
          int tok  = ltok[soff+row];
          float* orow = out + (size_t)tok*HID;
          #pragma unroll
          for (int n=0;n<4;n++){
            int col = n0 + wc + n*16 + l15;
            atomicAdd(orow + col, sw*(acc[m][n][j] + b2[(size_t)e*HID + col]));
          }
        }
      }
    }
  }
}

extern "C" void kernel_launch(void* const* d_in, const int* in_sizes, int n_in,
                              void* d_out, int out_size, void* d_ws, size_t ws_size,
                              hipStream_t stream){
  const float* x  = (const float*)d_in[0];
  const float* Wg = (const float*)d_in[1];
  const float* bg = (const float*)d_in[2];
  const float* W1 = (const float*)d_in[3];
  const float* b1 = (const float*)d_in[4];
  const float* W2 = (const float*)d_in[5];
  const float* b2 = (const float*)d_in[6];
  float* out = (float*)d_out;

  char* ws = (char*)d_ws;
  size_t off = 0;
  u16* SLOT_A = (u16*)(ws + off); off += (size_t)NE*FFN*HID*2;   // W1T, then W2T
  u16* XB  = (u16*)(ws + off); off += (size_t)NTOK*HID*2;
  u16* HDN = (u16*)(ws + off); off += (size_t)NPAIR*FFN*2;
  int*   LTOK = (int*)(ws + off);   off += (size_t)NPAIR*4;
  float* LW   = (float*)(ws + off); off += (size_t)NPAIR*4;
  int*   TKE  = (int*)(ws + off);   off += (size_t)NPAIR*4;
  float* TKW  = (float*)(ws + off); off += (size_t)NPAIR*4;
  int*   CTRL = (int*)(ws + off);   off += 256;
  int* counts  = CTRL;
  int* offsets = CTRL + 16;
  int* cursors = CTRL + 33;

  (void)hipMemsetAsync(CTRL, 0, 256, stream);
  (void)hipMemsetAsync(out, 0, (size_t)NTOK*HID*sizeof(float), stream);

  k_gating<<<NTOK/4, 256, 0, stream>>>(x, Wg, bg, counts, TKE, TKW, XB);
  k_scatter<<<NTOK/256, 256, 0, stream>>>(TKE, TKW, counts, offsets, cursors, LTOK, LW);
  k_wcvt<<<2048, 256, 0, stream>>>(W1, SLOT_A, HID, FFN);
  k_ffn1<<<256, 512, 0, stream>>>(XB, SLOT_A, b1, counts, offsets, LTOK, HDN);
  k_wcvt<<<2048, 256, 0, stream>>>(W2, SLOT_A, FFN, HID);
  k_ffn2<<<256, 512, 0, stream>>>(HDN, SLOT_A, b2, counts, offsets, LTOK, LW, out);
}